// Round 1
// baseline (9183.832 us; speedup 1.0000x reference)
//
#include <hip/hip_runtime.h>
#include <math.h>

#define CHUNK 32
#define DK 128
#define DV 128
#define NT 512
#define L_SEQ 4096
#define BH 32

__global__ __launch_bounds__(NT, 1)
void deltanet_kernel(const float* __restrict__ q,
                     const float* __restrict__ k,
                     const float* __restrict__ v,
                     const float* __restrict__ beta,
                     float* __restrict__ out)
{
    const int bh = blockIdx.x;   // 0..31
    const int tid = threadIdx.x; // 0..511
    const int n = L_SEQ / CHUNK; // 128

    // LDS: ~137 KB total (fits 160 KB/CU). stride padded to 129 floats
    // so column-indexed reads (lanes vary col) are bank-conflict-free.
    __shared__ float S[DK][DV + 1];          // 66,048 B  state
    __shared__ float qs[CHUNK][DK + 1];      // 16,512 B
    __shared__ float ks[CHUNK][DK + 1];      // 16,512 B
    __shared__ float vs[CHUNK][DV + 1];      // 16,512 B  (v*beta, then u0, then u_i)
    __shared__ float kbs[CHUNK][DK + 1];     // 16,512 B  (k*beta, then w)
    __shared__ float T[CHUNK][CHUNK + 1];    //  4,224 B
    __shared__ float at[CHUNK][CHUNK + 1];   //  4,224 B  (scales scratch, then attn)
    __shared__ float bet[CHUNK];

    // zero state
    for (int idx = tid; idx < DK * DV; idx += NT)
        S[idx / DV][idx % DV] = 0.f;
    __syncthreads();

    const size_t base_bh = (size_t)bh * L_SEQ;

    for (int ch = 0; ch < n; ++ch) {
        const size_t row0 = base_bh + (size_t)ch * CHUNK;

        // ---- load raw tiles (coalesced: consecutive tid -> consecutive col)
        for (int idx = tid; idx < CHUNK * DK; idx += NT) {
            int r = idx >> 7, c = idx & 127;
            size_t g = (row0 + (size_t)r) * DK + c;
            qs[r][c] = q[g];
            ks[r][c] = k[g];
            vs[r][c] = v[g];
        }
        if (tid < CHUNK) bet[tid] = beta[row0 + tid];
        __syncthreads();

        // ---- row L2-norm scales: threads 0..31 -> q rows, 32..63 -> k rows
        if (tid < 64) {
            int r = tid & 31;
            const float* src = (tid < 32) ? &qs[r][0] : &ks[r][0];
            float s = 0.f;
            for (int d = 0; d < DK; ++d) { float x = src[d]; s += x * x; }
            at[(tid < 32) ? 0 : 1][r] = 1.0f / sqrtf(s + 1e-6f);
        }
        __syncthreads();

        // ---- normalize q,k; v *= beta; kb = k_norm * beta
        for (int idx = tid; idx < CHUNK * DK; idx += NT) {
            int r = idx >> 7, c = idx & 127;
            float qq = qs[r][c] * at[0][r];
            float kk = ks[r][c] * at[1][r];
            float b = bet[r];
            qs[r][c] = qq;
            ks[r][c] = kk;
            kbs[r][c] = kk * b;
            vs[r][c] = vs[r][c] * b;
        }
        __syncthreads();

        // ---- T = -(kb @ k^T) * strict_lower
        for (int idx = tid; idx < CHUNK * CHUNK; idx += NT) {
            int i = idx >> 5, j = idx & 31;
            float s = 0.f;
            if (j < i) {
                for (int d = 0; d < DK; ++d) s += kbs[i][d] * ks[j][d];
                s = -s;
            }
            T[i][j] = s;
        }
        __syncthreads();

        // ---- forward substitution: T[i][j] += sum_{j<kk<i} T[i][kk]*T[kk][j]
        for (int i = 1; i < CHUNK; ++i) {
            float upd = 0.f;
            if (tid < i) {
                int j = tid;
                for (int kk = j + 1; kk < i; ++kk) upd += T[i][kk] * T[kk][j];
            }
            __syncthreads();
            if (tid < i) T[i][tid] += upd;
            __syncthreads();
        }
        if (tid < CHUNK) T[tid][tid] = 1.0f;
        __syncthreads();

        // ---- u0 = T @ v  -> vs ;  w = T @ kb -> kbs (in-register, then writeback)
        {
            int c = tid & 127;
            int i0 = (tid >> 7) * 8; // 4 groups x 8 rows
            float uacc[8], wacc[8];
#pragma unroll
            for (int r = 0; r < 8; ++r) { uacc[r] = 0.f; wacc[r] = 0.f; }
            for (int j = 0; j < CHUNK; ++j) {
                float vv = vs[j][c];
                float kb = kbs[j][c];
#pragma unroll
                for (int r = 0; r < 8; ++r) {
                    float t = T[i0 + r][j]; // wave-uniform -> broadcast
                    uacc[r] += t * vv;
                    wacc[r] += t * kb;
                }
            }
            __syncthreads();
#pragma unroll
            for (int r = 0; r < 8; ++r) {
                vs[i0 + r][c] = uacc[r];
                kbs[i0 + r][c] = wacc[r];
            }
        }
        __syncthreads();

        // ---- attn = (q @ k^T) * lower_inc   (overwrites scale scratch)
        for (int idx = tid; idx < CHUNK * CHUNK; idx += NT) {
            int i = idx >> 5, j = idx & 31;
            float s = 0.f;
            if (j <= i) {
                for (int d = 0; d < DK; ++d) s += qs[i][d] * ks[j][d];
            }
            at[i][j] = s;
        }
        __syncthreads();

        // ---- u_i = u0 - w @ S   (vs <- vs - kbs @ S)
        {
            int c = tid & 127;
            int i0 = (tid >> 7) * 8;
            float acc[8];
#pragma unroll
            for (int r = 0; r < 8; ++r) acc[r] = 0.f;
            for (int d = 0; d < DK; ++d) {
                float sv = S[d][c]; // lanes vary c -> conflict-free
#pragma unroll
                for (int r = 0; r < 8; ++r)
                    acc[r] += kbs[i0 + r][d] * sv; // broadcast
            }
#pragma unroll
            for (int r = 0; r < 8; ++r)
                vs[i0 + r][c] -= acc[r]; // unique owner per (i,c)
        }
        __syncthreads();

        // ---- out = q @ S + attn @ u_i  (coalesced global store)
        {
            int c = tid & 127;
            int i0 = (tid >> 7) * 8;
            float acc[8];
#pragma unroll
            for (int r = 0; r < 8; ++r) acc[r] = 0.f;
            for (int d = 0; d < DK; ++d) {
                float sv = S[d][c];
#pragma unroll
                for (int r = 0; r < 8; ++r)
                    acc[r] += qs[i0 + r][d] * sv;
            }
            for (int j = 0; j < CHUNK; ++j) {
                float uv = vs[j][c];
#pragma unroll
                for (int r = 0; r < 8; ++r)
                    acc[r] += at[i0 + r][j] * uv;
            }
#pragma unroll
            for (int r = 0; r < 8; ++r)
                out[(row0 + (size_t)(i0 + r)) * DV + c] = acc[r];
        }
        __syncthreads(); // all reads of old S done

        // ---- S += k^T @ u_i
        {
            int c = tid & 127;
            int d0 = (tid >> 7) * 32;
            float acc[32];
#pragma unroll
            for (int r = 0; r < 32; ++r) acc[r] = 0.f;
            for (int i = 0; i < CHUNK; ++i) {
                float uv = vs[i][c];
#pragma unroll
                for (int r = 0; r < 32; ++r)
                    acc[r] += ks[i][d0 + r] * uv; // broadcast
            }
#pragma unroll
            for (int r = 0; r < 32; ++r)
                S[d0 + r][c] += acc[r];
        }
        __syncthreads();
    }
}

extern "C" void kernel_launch(void* const* d_in, const int* in_sizes, int n_in,
                              void* d_out, int out_size, void* d_ws, size_t ws_size,
                              hipStream_t stream) {
    const float* q = (const float*)d_in[0];
    const float* k = (const float*)d_in[1];
    const float* v = (const float*)d_in[2];
    const float* beta = (const float*)d_in[3];
    float* out = (float*)d_out;
    deltanet_kernel<<<BH, NT, 0, stream>>>(q, k, v, beta, out);
}

// Round 2
// 845.172 us; speedup vs baseline: 10.8662x; 10.8662x over previous
//
#include <hip/hip_runtime.h>
#include <math.h>

#define CHUNK 32
#define DK 128
#define DV 128
#define L_SEQ 4096
#define BH 32
#define NCH 128

typedef __attribute__((ext_vector_type(8))) short bf16x8;
typedef __attribute__((ext_vector_type(4))) float f32x4;
typedef __attribute__((ext_vector_type(4))) unsigned short us4;
typedef __attribute__((ext_vector_type(8))) unsigned short us8;

__device__ __forceinline__ unsigned short f2bf(float x){
    unsigned int u = __builtin_bit_cast(unsigned int, x);
    u = u + 0x7FFFu + ((u >> 16) & 1u);   // RNE
    return (unsigned short)(u >> 16);
}

// ---------------- Phase 1: fully parallel per-chunk prep -------------------
// one block per (bh, chunk): computes T = (I + strict_lower(kb k^T))^{-1}
// via Neumann doubling, attn = tril(qn kn^T), and q/k row-norm scales.

__device__ __forceinline__ void mm32(float (*P)[33], const float (*X)[33],
                                     const float (*Y)[33], int t){
    for (int idx = t; idx < 1024; idx += 256){
        int i = idx >> 5, j = idx & 31;
        float s = 0.f;
        for (int kk = j; kk <= i; ++kk) s += X[i][kk] * Y[kk][j];
        P[i][j] = s;
    }
}
__device__ __forceinline__ void addP(float (*P)[33], const float (*D)[33], int t){
    for (int idx = t; idx < 1024; idx += 256){
        int i = idx >> 5, j = idx & 31;
        P[i][j] += D[i][j];
    }
}

__global__ __launch_bounds__(256, 2)
void prep_kernel(const float* __restrict__ q, const float* __restrict__ k,
                 const float* __restrict__ beta,
                 float* __restrict__ Tws, float* __restrict__ Aws,
                 float* __restrict__ qscw, float* __restrict__ kscw)
{
    const int bc = blockIdx.x;               // bh*NCH + ch
    const size_t row0 = (size_t)bc * CHUNK;  // global row
    const int t = threadIdx.x;

    __shared__ float qt[32][132], kt[32][132], kbt[32][132];
    __shared__ float Bm[32][33], Cm[32][33], Dm[32][33], Rm[32][33];
    __shared__ float parq[32][8], park[32][8];
    __shared__ float scq[32], sck[32], bet[32];

    const int r = t >> 3, s8 = t & 7, d0 = s8 * 16;
    {
        const float4* qp = (const float4*)(q + (row0 + r) * DK + d0);
        const float4* kp = (const float4*)(k + (row0 + r) * DK + d0);
        float sq = 0.f, sk = 0.f;
#pragma unroll
        for (int j = 0; j < 4; ++j){
            float4 a = qp[j], b = kp[j];
            *(float4*)&qt[r][d0 + 4*j] = a;
            *(float4*)&kt[r][d0 + 4*j] = b;
            sq += a.x*a.x + a.y*a.y + a.z*a.z + a.w*a.w;
            sk += b.x*b.x + b.y*b.y + b.z*b.z + b.w*b.w;
        }
        parq[r][s8] = sq; park[r][s8] = sk;
    }
    if (t < 32) bet[t] = beta[row0 + t];
    __syncthreads();
    if (t < 32){
        float s = 0.f;
        for (int j = 0; j < 8; ++j) s += parq[t][j];
        float sc = rsqrtf(s + 1e-6f); scq[t] = sc; qscw[row0 + t] = sc;
    } else if (t < 64){
        int rr = t - 32;
        float s = 0.f;
        for (int j = 0; j < 8; ++j) s += park[rr][j];
        float sc = rsqrtf(s + 1e-6f); sck[rr] = sc; kscw[row0 + rr] = sc;
    }
    __syncthreads();
    {
        float aq = scq[r], ak = sck[r], bb = bet[r];
        for (int j = 0; j < 16; ++j){
            qt[r][d0 + j] *= aq;
            float kk = kt[r][d0 + j] * ak;
            kt[r][d0 + j] = kk;
            kbt[r][d0 + j] = kk * bb;
        }
    }
    __syncthreads();
    // B = -(kb @ kn^T) strict lower
    for (int idx = t; idx < 1024; idx += 256){
        int i = idx >> 5, j = idx & 31;
        float s = 0.f;
        if (j < i){
            const float4* a = (const float4*)&kbt[i][0];
            const float4* b = (const float4*)&kt[j][0];
            for (int d = 0; d < 32; ++d){
                float4 x = a[d], y = b[d];
                s += x.x*y.x + x.y*y.y + x.z*y.z + x.w*y.w;
            }
            s = -s;
        }
        Bm[i][j] = s;
    }
    // attn = tril(qn kn^T) -> global directly
    for (int idx = t; idx < 1024; idx += 256){
        int i = idx >> 5, j = idx & 31;
        float s = 0.f;
        if (j <= i){
            const float4* a = (const float4*)&qt[i][0];
            const float4* b = (const float4*)&kt[j][0];
            for (int d = 0; d < 32; ++d){
                float4 x = a[d], y = b[d];
                s += x.x*y.x + x.y*y.y + x.z*y.z + x.w*y.w;
            }
        }
        Aws[(size_t)bc * 1024 + idx] = s;
    }
    __syncthreads();
    // R = I + B; then R *= (I+B^2)(I+B^4)(I+B^8)(I+B^16) via doubling
    for (int idx = t; idx < 1024; idx += 256){
        int i = idx >> 5, j = idx & 31;
        Rm[i][j] = Bm[i][j] + (i == j ? 1.f : 0.f);
    }
    __syncthreads();
    mm32(Cm, Bm, Bm, t); __syncthreads();                       // C = B^2
    mm32(Dm, Rm, Cm, t); __syncthreads(); addP(Rm, Dm, t); __syncthreads();
    mm32(Bm, Cm, Cm, t); __syncthreads();                       // B <- B^4
    mm32(Dm, Rm, Bm, t); __syncthreads(); addP(Rm, Dm, t); __syncthreads();
    mm32(Cm, Bm, Bm, t); __syncthreads();                       // C <- B^8
    mm32(Dm, Rm, Cm, t); __syncthreads(); addP(Rm, Dm, t); __syncthreads();
    mm32(Bm, Cm, Cm, t); __syncthreads();                       // B <- B^16
    mm32(Dm, Rm, Bm, t); __syncthreads(); addP(Rm, Dm, t); __syncthreads();
    for (int idx = t; idx < 1024; idx += 256)
        Tws[(size_t)bc * 1024 + idx] = Rm[idx >> 5][idx & 31];
}

// ---------------- Phase 2: sequential chunk scan, MFMA, col-split ----------
// grid (8, 32): blockIdx.y = bh, blockIdx.x = 16-col slice of dv.
// State S kept transposed (c x d) as fp32 MFMA accumulators (32 VGPR/lane),
// re-staged to LDS as bf16 each chunk for use as B-operand.

__global__ __launch_bounds__(128)
void scan_kernel(const float* __restrict__ q, const float* __restrict__ k,
                 const float* __restrict__ v, const float* __restrict__ beta,
                 const float* __restrict__ Tws, const float* __restrict__ Aws,
                 const float* __restrict__ qscw, const float* __restrict__ kscw,
                 float* __restrict__ out)
{
    const int cb = blockIdx.x;          // 0..7
    const int bh = blockIdx.y;          // 0..31
    const int c0 = cb * 16;
    const int t = threadIdx.x;
    const int w = t >> 6;               // wave 0/1
    const int lane = t & 63;
    const int quad = lane >> 4;
    const int ln15 = lane & 15;
    const int m0 = 16 * w;
    const int q8 = quad * 8;

    __shared__ unsigned short qb[32][136];   // qn rows (bf16)
    __shared__ unsigned short knR[32][136];  // kn rows
    __shared__ unsigned short knT[128][40];  // kn transposed [d][i]
    __shared__ unsigned short Stb[16][136];  // S^T (c x d) bf16 copy
    __shared__ unsigned short Tb[32][40];
    __shared__ unsigned short Ab[32][40];
    __shared__ unsigned short Xt[16][40];    // X^T (c x i)
    __shared__ unsigned short ut[16][40];    // u^T (c x i)
    __shared__ float vbs[32][20];
    __shared__ float bet[32];

    const int rr  = t >> 2;     // staging row 0..31
    const int seg = t & 3;
    const int dd0 = seg * 32;

    f32x4 Sacc[4];
#pragma unroll
    for (int tt = 0; tt < 4; ++tt){ Sacc[tt][0]=0.f; Sacc[tt][1]=0.f; Sacc[tt][2]=0.f; Sacc[tt][3]=0.f; }

    float4 pq[8], pk[8], pT[2], pA[2], pv;
    float pscq, psck, pbt, pb32;

    const size_t bhL = (size_t)bh * L_SEQ;

    // prefetch chunk ch into registers
    auto issue_loads = [&](int ch){
        size_t row0 = bhL + (size_t)ch * CHUNK;
        const float4* qp = (const float4*)(q + (row0 + rr) * DK + dd0);
        const float4* kp = (const float4*)(k + (row0 + rr) * DK + dd0);
#pragma unroll
        for (int j = 0; j < 8; ++j){ pq[j] = qp[j]; pk[j] = kp[j]; }
        size_t tb = ((size_t)bh * NCH + ch) * 1024 + (size_t)t * 8;
        pT[0] = *(const float4*)(Tws + tb);
        pT[1] = *(const float4*)(Tws + tb + 4);
        pA[0] = *(const float4*)(Aws + tb);
        pA[1] = *(const float4*)(Aws + tb + 4);
        pv = *(const float4*)(v + (row0 + rr) * DV + c0 + seg * 4);
        pscq = qscw[row0 + rr];
        psck = kscw[row0 + rr];
        pbt  = beta[row0 + rr];
        pb32 = (t < 32) ? beta[row0 + t] : 0.f;
    };

    issue_loads(0);

    for (int ch = 0; ch < NCH; ++ch){
        // ---- stage prefetched regs -> LDS (bf16) ----
#pragma unroll
        for (int j = 0; j < 8; ++j){
            float4 a = pq[j];
            us4 pa; pa[0]=f2bf(a.x*pscq); pa[1]=f2bf(a.y*pscq); pa[2]=f2bf(a.z*pscq); pa[3]=f2bf(a.w*pscq);
            *(us4*)(void*)&qb[rr][dd0 + 4*j] = pa;
            float4 b = pk[j];
            unsigned short k0=f2bf(b.x*psck), k1=f2bf(b.y*psck), k2=f2bf(b.z*psck), k3=f2bf(b.w*psck);
            us4 pb; pb[0]=k0; pb[1]=k1; pb[2]=k2; pb[3]=k3;
            *(us4*)(void*)&knR[rr][dd0 + 4*j] = pb;
            knT[dd0 + 4*j + 0][rr] = k0;
            knT[dd0 + 4*j + 1][rr] = k1;
            knT[dd0 + 4*j + 2][rr] = k2;
            knT[dd0 + 4*j + 3][rr] = k3;
        }
        {
            us8 pt, pa;
            pt[0]=f2bf(pT[0].x); pt[1]=f2bf(pT[0].y); pt[2]=f2bf(pT[0].z); pt[3]=f2bf(pT[0].w);
            pt[4]=f2bf(pT[1].x); pt[5]=f2bf(pT[1].y); pt[6]=f2bf(pT[1].z); pt[7]=f2bf(pT[1].w);
            *(us8*)(void*)&Tb[rr][seg * 8] = pt;
            pa[0]=f2bf(pA[0].x); pa[1]=f2bf(pA[0].y); pa[2]=f2bf(pA[0].z); pa[3]=f2bf(pA[0].w);
            pa[4]=f2bf(pA[1].x); pa[5]=f2bf(pA[1].y); pa[6]=f2bf(pA[1].z); pa[7]=f2bf(pA[1].w);
            *(us8*)(void*)&Ab[rr][seg * 8] = pa;
        }
        {
            float4 x = pv;
            x.x *= pbt; x.y *= pbt; x.z *= pbt; x.w *= pbt;
            *(float4*)&vbs[rr][seg * 4] = x;
        }
        if (t < 32) bet[t] = pb32;
        // S^T fp32 accumulators -> bf16 LDS copy
#pragma unroll
        for (int tt = 0; tt < 4; ++tt){
#pragma unroll
            for (int rg = 0; rg < 4; ++rg)
                Stb[quad * 4 + rg][w * 64 + tt * 16 + ln15] = f2bf(Sacc[tt][rg]);
        }
        __syncthreads();

        if (ch + 1 < NCH) issue_loads(ch + 1);  // overlap next-chunk loads with compute

        // ---- step b: Y = kn @ S^T  (this wave's 16 rows) ----
        f32x4 Y; Y[0]=0.f; Y[1]=0.f; Y[2]=0.f; Y[3]=0.f;
#pragma unroll
        for (int ks = 0; ks < 4; ++ks){
            bf16x8 a = *(const bf16x8*)(const void*)&knR[m0 + ln15][ks * 32 + q8];
            bf16x8 b = *(const bf16x8*)(const void*)&Stb[ln15][ks * 32 + q8];
            Y = __builtin_amdgcn_mfma_f32_16x16x32_bf16(a, b, Y, 0, 0, 0);
        }
        // X = v*beta - beta*(kn.S)  -> Xt (c x i) bf16
        {
            us4 xs;
#pragma unroll
            for (int rg = 0; rg < 4; ++rg){
                int i = m0 + quad * 4 + rg;
                float xv = vbs[i][ln15] - bet[i] * Y[rg];
                xs[rg] = f2bf(xv);
            }
            *(us4*)(void*)&Xt[ln15][m0 + quad * 4] = xs;
        }
        __syncthreads();

        // ---- step c: U = T @ X ----
        f32x4 U; U[0]=0.f; U[1]=0.f; U[2]=0.f; U[3]=0.f;
        {
            bf16x8 a = *(const bf16x8*)(const void*)&Tb[m0 + ln15][q8];
            bf16x8 b = *(const bf16x8*)(const void*)&Xt[ln15][q8];
            U = __builtin_amdgcn_mfma_f32_16x16x32_bf16(a, b, U, 0, 0, 0);
        }
        {
            us4 usv;
#pragma unroll
            for (int rg = 0; rg < 4; ++rg) usv[rg] = f2bf(U[rg]);
            *(us4*)(void*)&ut[ln15][m0 + quad * 4] = usv;
        }
        __syncthreads();

        // ---- step d: O = qn @ S^T + attn @ U ; store out ----
        f32x4 O; O[0]=0.f; O[1]=0.f; O[2]=0.f; O[3]=0.f;
#pragma unroll
        for (int ks = 0; ks < 4; ++ks){
            bf16x8 a = *(const bf16x8*)(const void*)&qb[m0 + ln15][ks * 32 + q8];
            bf16x8 b = *(const bf16x8*)(const void*)&Stb[ln15][ks * 32 + q8];
            O = __builtin_amdgcn_mfma_f32_16x16x32_bf16(a, b, O, 0, 0, 0);
        }
        {
            bf16x8 a = *(const bf16x8*)(const void*)&Ab[m0 + ln15][q8];
            bf16x8 b = *(const bf16x8*)(const void*)&ut[ln15][q8];
            O = __builtin_amdgcn_mfma_f32_16x16x32_bf16(a, b, O, 0, 0, 0);
        }
        {
            size_t row0 = bhL + (size_t)ch * CHUNK;
#pragma unroll
            for (int rg = 0; rg < 4; ++rg)
                out[(row0 + m0 + quad * 4 + rg) * DV + c0 + ln15] = O[rg];
        }

        // ---- step e: S^T += u^T @ kn  (accumulate in place, fp32) ----
        {
            bf16x8 a = *(const bf16x8*)(const void*)&ut[ln15][q8];
#pragma unroll
            for (int tt = 0; tt < 4; ++tt){
                bf16x8 b = *(const bf16x8*)(const void*)&knT[w * 64 + tt * 16 + ln15][q8];
                Sacc[tt] = __builtin_amdgcn_mfma_f32_16x16x32_bf16(a, b, Sacc[tt], 0, 0, 0);
            }
        }
        __syncthreads();   // protect LDS before next chunk's staging
    }
}

// ---------------- Fallback (round-1 kernel) if ws too small ----------------

__global__ __launch_bounds__(512, 1)
void deltanet_fused(const float* __restrict__ q, const float* __restrict__ k,
                    const float* __restrict__ v, const float* __restrict__ beta,
                    float* __restrict__ out)
{
    const int bh = blockIdx.x;
    const int tid = threadIdx.x;
    const int n = L_SEQ / CHUNK;

    __shared__ float S[DK][DV + 1];
    __shared__ float qs[CHUNK][DK + 1];
    __shared__ float ks[CHUNK][DK + 1];
    __shared__ float vs[CHUNK][DV + 1];
    __shared__ float kbs[CHUNK][DK + 1];
    __shared__ float T[CHUNK][CHUNK + 1];
    __shared__ float at[CHUNK][CHUNK + 1];
    __shared__ float bet[CHUNK];

    for (int idx = tid; idx < DK * DV; idx += 512)
        S[idx / DV][idx % DV] = 0.f;
    __syncthreads();

    const size_t base_bh = (size_t)bh * L_SEQ;

    for (int ch = 0; ch < n; ++ch){
        const size_t row0 = base_bh + (size_t)ch * CHUNK;
        for (int idx = tid; idx < CHUNK * DK; idx += 512){
            int r = idx >> 7, c = idx & 127;
            size_t g = (row0 + (size_t)r) * DK + c;
            qs[r][c] = q[g]; ks[r][c] = k[g]; vs[r][c] = v[g];
        }
        if (tid < CHUNK) bet[tid] = beta[row0 + tid];
        __syncthreads();
        if (tid < 64){
            int r = tid & 31;
            const float* src = (tid < 32) ? &qs[r][0] : &ks[r][0];
            float s = 0.f;
            for (int d = 0; d < DK; ++d){ float x = src[d]; s += x * x; }
            at[(tid < 32) ? 0 : 1][r] = 1.0f / sqrtf(s + 1e-6f);
        }
        __syncthreads();
        for (int idx = tid; idx < CHUNK * DK; idx += 512){
            int r = idx >> 7, c = idx & 127;
            float qq = qs[r][c] * at[0][r];
            float kk = ks[r][c] * at[1][r];
            float b = bet[r];
            qs[r][c] = qq; ks[r][c] = kk; kbs[r][c] = kk * b; vs[r][c] *= b;
        }
        __syncthreads();
        for (int idx = tid; idx < CHUNK * CHUNK; idx += 512){
            int i = idx >> 5, j = idx & 31;
            float s = 0.f;
            if (j < i){
                for (int d = 0; d < DK; ++d) s += kbs[i][d] * ks[j][d];
                s = -s;
            }
            T[i][j] = s;
        }
        __syncthreads();
        for (int i = 1; i < CHUNK; ++i){
            float upd = 0.f;
            if (tid < i){
                int j = tid;
                for (int kk = j + 1; kk < i; ++kk) upd += T[i][kk] * T[kk][j];
            }
            __syncthreads();
            if (tid < i) T[i][tid] += upd;
            __syncthreads();
        }
        if (tid < CHUNK) T[tid][tid] = 1.0f;
        __syncthreads();
        {
            int c = tid & 127;
            int i0 = (tid >> 7) * 8;
            float uacc[8], wacc[8];
#pragma unroll
            for (int r = 0; r < 8; ++r){ uacc[r] = 0.f; wacc[r] = 0.f; }
            for (int j = 0; j < CHUNK; ++j){
                float vv = vs[j][c], kb = kbs[j][c];
#pragma unroll
                for (int r = 0; r < 8; ++r){
                    float tt = T[i0 + r][j];
                    uacc[r] += tt * vv; wacc[r] += tt * kb;
                }
            }
            __syncthreads();
#pragma unroll
            for (int r = 0; r < 8; ++r){ vs[i0 + r][c] = uacc[r]; kbs[i0 + r][c] = wacc[r]; }
        }
        __syncthreads();
        for (int idx = tid; idx < CHUNK * CHUNK; idx += 512){
            int i = idx >> 5, j = idx & 31;
            float s = 0.f;
            if (j <= i) for (int d = 0; d < DK; ++d) s += qs[i][d] * ks[j][d];
            at[i][j] = s;
        }
        __syncthreads();
        {
            int c = tid & 127;
            int i0 = (tid >> 7) * 8;
            float acc[8];
#pragma unroll
            for (int r = 0; r < 8; ++r) acc[r] = 0.f;
            for (int d = 0; d < DK; ++d){
                float sv = S[d][c];
#pragma unroll
                for (int r = 0; r < 8; ++r) acc[r] += kbs[i0 + r][d] * sv;
            }
#pragma unroll
            for (int r = 0; r < 8; ++r) vs[i0 + r][c] -= acc[r];
        }
        __syncthreads();
        {
            int c = tid & 127;
            int i0 = (tid >> 7) * 8;
            float acc[8];
#pragma unroll
            for (int r = 0; r < 8; ++r) acc[r] = 0.f;
            for (int d = 0; d < DK; ++d){
                float sv = S[d][c];
#pragma unroll
                for (int r = 0; r < 8; ++r) acc[r] += qs[i0 + r][d] * sv;
            }
            for (int j = 0; j < CHUNK; ++j){
                float uv = vs[j][c];
#pragma unroll
                for (int r = 0; r < 8; ++r) acc[r] += at[i0 + r][j] * uv;
            }
#pragma unroll
            for (int r = 0; r < 8; ++r)
                out[(row0 + (size_t)(i0 + r)) * DV + c] = acc[r];
        }
        __syncthreads();
        {
            int c = tid & 127;
            int d0 = (tid >> 7) * 32;
            float acc[32];
#pragma unroll
            for (int r = 0; r < 32; ++r) acc[r] = 0.f;
            for (int i = 0; i < CHUNK; ++i){
                float uv = vs[i][c];
#pragma unroll
                for (int r = 0; r < 32; ++r) acc[r] += ks[i][d0 + r] * uv;
            }
#pragma unroll
            for (int r = 0; r < 32; ++r) S[d0 + r][c] += acc[r];
        }
        __syncthreads();
    }
}

extern "C" void kernel_launch(void* const* d_in, const int* in_sizes, int n_in,
                              void* d_out, int out_size, void* d_ws, size_t ws_size,
                              hipStream_t stream) {
    const float* q = (const float*)d_in[0];
    const float* k = (const float*)d_in[1];
    const float* v = (const float*)d_in[2];
    const float* beta = (const float*)d_in[3];
    float* out = (float*)d_out;

    const size_t needf = (size_t)2 * BH * NCH * 1024 + (size_t)2 * BH * L_SEQ;
    if (ws_size >= needf * sizeof(float)){
        float* Tws  = (float*)d_ws;
        float* Aws  = Tws + (size_t)BH * NCH * 1024;
        float* qscw = Aws + (size_t)BH * NCH * 1024;
        float* kscw = qscw + (size_t)BH * L_SEQ;
        prep_kernel<<<BH * NCH, 256, 0, stream>>>(q, k, beta, Tws, Aws, qscw, kscw);
        scan_kernel<<<dim3(8, BH), 128, 0, stream>>>(q, k, v, beta, Tws, Aws, qscw, kscw, out);
    } else {
        deltanet_fused<<<BH, 512, 0, stream>>>(q, k, v, beta, out);
    }
}

// Round 4
// 501.243 us; speedup vs baseline: 18.3221x; 1.6862x over previous
//
#include <hip/hip_runtime.h>
#include <math.h>

#define CHUNK 32
#define DK 128
#define DV 128
#define L_SEQ 4096
#define BH 32
#define NCH 128

typedef __attribute__((ext_vector_type(8))) short bf16x8;
typedef __attribute__((ext_vector_type(4))) float f32x4;

union U8 { unsigned int u[4]; bf16x8 v; };

#define MFMA16(a, b, c) __builtin_amdgcn_mfma_f32_16x16x32_bf16((a), (b), (c), 0, 0, 0)
#define LGKM_WAIT() __asm__ __volatile__("s_waitcnt lgkmcnt(0)" ::: "memory")

__device__ __forceinline__ unsigned short f2bf(float x){
    unsigned int u = __builtin_bit_cast(unsigned int, x);
    u = u + 0x7FFFu + ((u >> 16) & 1u);   // RNE
    return (unsigned short)(u >> 16);
}
__device__ __forceinline__ unsigned int pk2(float a, float b){
    return (unsigned int)f2bf(a) | ((unsigned int)f2bf(b) << 16);
}

__device__ __forceinline__ bf16x8 afragF32(const float (*M)[36], int row, int q8){
    float4 f0 = *(const float4*)&M[row][q8];
    float4 f1 = *(const float4*)&M[row][q8 + 4];
    U8 t;
    t.u[0] = pk2(f0.x, f0.y); t.u[1] = pk2(f0.z, f0.w);
    t.u[2] = pk2(f1.x, f1.y); t.u[3] = pk2(f1.z, f1.w);
    return t.v;
}
__device__ __forceinline__ bf16x8 bfragF32(const float (*M)[36], int q8, int col){
    U8 t;
#pragma unroll
    for (int j2 = 0; j2 < 4; ++j2)
        t.u[j2] = pk2(M[q8 + 2*j2][col], M[q8 + 2*j2 + 1][col]);
    return t.v;
}

// ---------------- Phase 1: fully parallel per-chunk prep (MFMA) ------------
// One 64-thread block per (bh,chunk). Outputs to ws:
//   qw/kw : bf16, L2-normalized q/k rows  [bh][L][128]
//   Tw    : bf16 T = (I+A)^{-1}           [bh][nch][32][32]
//   Aw    : bf16 attn = tril(qn kn^T)     [bh][nch][32][32]

__global__ __launch_bounds__(64, 1)
void prep_kernel(const float* __restrict__ q, const float* __restrict__ k,
                 const float* __restrict__ beta,
                 unsigned short* __restrict__ qw, unsigned short* __restrict__ kw,
                 unsigned short* __restrict__ Tw, unsigned short* __restrict__ Aw)
{
    const int bc = blockIdx.x;               // bh*NCH + ch
    const size_t row0 = (size_t)bc * CHUNK;
    const int l = threadIdx.x;
    const int r = l & 31, h = l >> 5;
    const int quad = (l >> 4) & 3, ln15 = l & 15, q8 = quad * 8;

    __shared__ unsigned short qn_s[32][136], kn_s[32][136], kb_s[32][136];
    __shared__ float Ms[32][36];
    __shared__ float Rs[32][36];

    const float bet = beta[row0 + r];

    // ---- load q row-half, normalize, cvt, stage + store ----
    {
        const float4* gp = (const float4*)(q + (row0 + r) * DK + 64 * h);
        float vb[64]; float s = 0.f;
#pragma unroll
        for (int e = 0; e < 16; ++e){
            float4 a = gp[e];
            vb[4*e+0]=a.x; vb[4*e+1]=a.y; vb[4*e+2]=a.z; vb[4*e+3]=a.w;
            s += a.x*a.x + a.y*a.y + a.z*a.z + a.w*a.w;
        }
        s += __shfl_xor(s, 32);
        float sc = rsqrtf(s + 1e-6f);
#pragma unroll
        for (int e = 0; e < 8; ++e){
            U8 t;
#pragma unroll
            for (int j = 0; j < 4; ++j)
                t.u[j] = pk2(vb[8*e+2*j] * sc, vb[8*e+2*j+1] * sc);
            *(bf16x8*)&qn_s[r][64*h + 8*e] = t.v;
            *(bf16x8*)(qw + (row0 + r) * DK + 64*h + 8*e) = t.v;
        }
    }
    // ---- k: kn + kb = kn*beta ----
    {
        const float4* gp = (const float4*)(k + (row0 + r) * DK + 64 * h);
        float vb[64]; float s = 0.f;
#pragma unroll
        for (int e = 0; e < 16; ++e){
            float4 a = gp[e];
            vb[4*e+0]=a.x; vb[4*e+1]=a.y; vb[4*e+2]=a.z; vb[4*e+3]=a.w;
            s += a.x*a.x + a.y*a.y + a.z*a.z + a.w*a.w;
        }
        s += __shfl_xor(s, 32);
        float sc = rsqrtf(s + 1e-6f);
#pragma unroll
        for (int e = 0; e < 8; ++e){
            U8 t, tb;
#pragma unroll
            for (int j = 0; j < 4; ++j){
                float x0 = vb[8*e+2*j] * sc, x1 = vb[8*e+2*j+1] * sc;
                t.u[j]  = pk2(x0, x1);
                tb.u[j] = pk2(x0 * bet, x1 * bet);
            }
            *(bf16x8*)&kn_s[r][64*h + 8*e] = t.v;
            *(bf16x8*)&kb_s[r][64*h + 8*e] = tb.v;
            *(bf16x8*)(kw + (row0 + r) * DK + 64*h + 8*e) = t.v;
        }
    }
    LGKM_WAIT();

    // ---- B = kb @ kn^T ; attn = qn @ kn^T  (MFMA, K=128) ----
    f32x4 Z = {0.f, 0.f, 0.f, 0.f};
    f32x4 Bacc[2][2] = {{Z, Z}, {Z, Z}};
    f32x4 Aacc[2][2] = {{Z, Z}, {Z, Z}};
#pragma unroll
    for (int ks = 0; ks < 4; ++ks){
        bf16x8 bF[2];
        bF[0] = *(const bf16x8*)&kn_s[ln15][32*ks + q8];
        bF[1] = *(const bf16x8*)&kn_s[16 + ln15][32*ks + q8];
#pragma unroll
        for (int mt = 0; mt < 2; ++mt){
            bf16x8 aK = *(const bf16x8*)&kb_s[16*mt + ln15][32*ks + q8];
            bf16x8 aQ = *(const bf16x8*)&qn_s[16*mt + ln15][32*ks + q8];
#pragma unroll
            for (int nt = 0; nt < 2; ++nt){
                Bacc[mt][nt] = MFMA16(aK, bF[nt], Bacc[mt][nt]);
                Aacc[mt][nt] = MFMA16(aQ, bF[nt], Aacc[mt][nt]);
            }
        }
    }

    // ---- masks; store attn; stage B; init R = I + B ----
    f32x4 Rc[2][2];
#pragma unroll
    for (int mt = 0; mt < 2; ++mt)
#pragma unroll
    for (int nt = 0; nt < 2; ++nt)
#pragma unroll
    for (int rg = 0; rg < 4; ++rg){
        int row = 16*mt + 4*quad + rg, col = 16*nt + ln15;
        float av = (col <= row) ? Aacc[mt][nt][rg] : 0.f;
        Aw[((size_t)bc << 10) + row*32 + col] = f2bf(av);
        float bm = (col < row) ? -Bacc[mt][nt][rg] : 0.f;
        Ms[row][col] = bm;
        Rc[mt][nt][rg] = bm + ((col == row) ? 1.f : 0.f);
    }

    // ---- doubling: R <- R(I+B^2)(I+B^4)(I+B^8)(I+B^16) ----
#pragma unroll 1
    for (int rd = 0; rd < 4; ++rd){
        LGKM_WAIT();
        bf16x8 Am[2], Bm2[2];
#pragma unroll
        for (int mt = 0; mt < 2; ++mt) Am[mt] = afragF32(Ms, 16*mt + ln15, q8);
#pragma unroll
        for (int nt = 0; nt < 2; ++nt) Bm2[nt] = bfragF32(Ms, q8, 16*nt + ln15);
        f32x4 Mq[2][2];
#pragma unroll
        for (int mt = 0; mt < 2; ++mt)
#pragma unroll
        for (int nt = 0; nt < 2; ++nt)
            Mq[mt][nt] = MFMA16(Am[mt], Bm2[nt], Z);
        // stage R and M^2
#pragma unroll
        for (int mt = 0; mt < 2; ++mt)
#pragma unroll
        for (int nt = 0; nt < 2; ++nt)
#pragma unroll
        for (int rg = 0; rg < 4; ++rg){
            int row = 16*mt + 4*quad + rg, col = 16*nt + ln15;
            Rs[row][col] = Rc[mt][nt][rg];
            Ms[row][col] = Mq[mt][nt][rg];
        }
        LGKM_WAIT();
        bf16x8 Ar[2], Bq[2];
#pragma unroll
        for (int mt = 0; mt < 2; ++mt) Ar[mt] = afragF32(Rs, 16*mt + ln15, q8);
#pragma unroll
        for (int nt = 0; nt < 2; ++nt) Bq[nt] = bfragF32(Ms, q8, 16*nt + ln15);
#pragma unroll
        for (int mt = 0; mt < 2; ++mt)
#pragma unroll
        for (int nt = 0; nt < 2; ++nt)
            Rc[mt][nt] = MFMA16(Ar[mt], Bq[nt], Rc[mt][nt]);   // R += R~ * M^2
    }

    // ---- store T ----
#pragma unroll
    for (int mt = 0; mt < 2; ++mt)
#pragma unroll
    for (int nt = 0; nt < 2; ++nt)
#pragma unroll
    for (int rg = 0; rg < 4; ++rg){
        int row = 16*mt + 4*quad + rg, col = 16*nt + ln15;
        Tw[((size_t)bc << 10) + row*32 + col] = f2bf(Rc[mt][nt][rg]);
    }
}

// ---------------- Phase 2: sequential scan — 1 wave/block, no barriers -----
// grid 256: id = bh + 32*cb (8 col-siblings of a bh land on one XCD).
// S master (d x c) in fp32 MFMA C-frags; B-frags built via ds_bpermute.

__global__ __launch_bounds__(64, 1)
void scan_kernel(const float* __restrict__ v, const float* __restrict__ beta,
                 const unsigned short* __restrict__ qw, const unsigned short* __restrict__ kw,
                 const unsigned short* __restrict__ Tw, const unsigned short* __restrict__ Aw,
                 float* __restrict__ out)
{
    const int id = blockIdx.x;
    const int bh = id & 31, cb = id >> 5, c0 = cb * 16;
    const int l = threadIdx.x;
    const int quad = (l >> 4) & 3, ln15 = l & 15, q8 = quad * 8;
    const int hi = l >> 5;

    __shared__ unsigned short knR[4392];   // row i at i*136 + (i>>3)*16 (bank-staggered)
    __shared__ unsigned short Xt[16][40];
    __shared__ unsigned short ut[16][40];

    const f32x4 Z = {0.f, 0.f, 0.f, 0.f};
    f32x4 Sacc[8];
#pragma unroll
    for (int t = 0; t < 8; ++t) Sacc[t] = Z;

    const size_t bhL = (size_t)bh * L_SEQ;
    const int a0 = (((l & 16) << 1) | ln15) << 2;   // bperm byte addr, quads 0/1
    const int a1 = a0 + 64;                          // quads 2/3

    bf16x8 kAa[2][4], kAb[2][4];

    auto loadK = [&](int ch, bf16x8 (&kA)[2][4]){
        const unsigned short* kp = kw + (bhL + (size_t)ch * CHUNK) * DK;
#pragma unroll
        for (int mt = 0; mt < 2; ++mt)
#pragma unroll
        for (int ks = 0; ks < 4; ++ks)
            kA[mt][ks] = *(const bf16x8*)(kp + (16*mt + ln15) * DK + 32*ks + q8);
    };

    loadK(0, kAa);

    auto body = [&](int ch, bf16x8 (&cur)[2][4], bf16x8 (&nxt)[2][4]){
        const size_t row0 = bhL + (size_t)ch * CHUNK;

        // current-chunk operand loads (consumed mid/late body)
        bf16x8 qA[2][4];
        {
            const unsigned short* qp = qw + row0 * DK;
#pragma unroll
            for (int mt = 0; mt < 2; ++mt)
#pragma unroll
            for (int ks = 0; ks < 4; ++ks)
                qA[mt][ks] = *(const bf16x8*)(qp + (16*mt + ln15) * DK + 32*ks + q8);
        }
        bf16x8 tA[2], aA[2];
        {
            const unsigned short* Tp = Tw + ((size_t)(bh * NCH + ch) << 10);
            const unsigned short* Ap = Aw + ((size_t)(bh * NCH + ch) << 10);
#pragma unroll
            for (int mt = 0; mt < 2; ++mt){
                tA[mt] = *(const bf16x8*)(Tp + (16*mt + ln15) * 32 + q8);
                aA[mt] = *(const bf16x8*)(Ap + (16*mt + ln15) * 32 + q8);
            }
        }
        float vv[8], bt[8];
#pragma unroll
        for (int g = 0; g < 8; ++g){
            int i = 16*(g >> 2) + 4*quad + (g & 3);
            vv[g] = v[(row0 + i) * DV + c0 + ln15];
            bt[g] = beta[row0 + i];
        }

        // stage kn rows -> knR (for S-update A-frags)
#pragma unroll
        for (int mt = 0; mt < 2; ++mt)
#pragma unroll
        for (int ks = 0; ks < 4; ++ks){
            int i = 16*mt + ln15;
            int ad = i * 136 + (i >> 3) * 16 + 32*ks + q8;
            *(bf16x8*)&knR[ad] = cur[mt][ks];
        }

        // S C-frags -> bf16 packed pairs -> B-frags via quad-bpermute
        int P[8][2];
#pragma unroll
        for (int t = 0; t < 8; ++t){
            P[t][0] = (int)pk2(Sacc[t][0], Sacc[t][1]);
            P[t][1] = (int)pk2(Sacc[t][2], Sacc[t][3]);
        }
        bf16x8 SB[4];
#pragma unroll
        for (int ks = 0; ks < 4; ++ks){
            U8 sb;
            int e, f;
            e = __builtin_amdgcn_ds_bpermute(a0, P[2*ks][0]);
            f = __builtin_amdgcn_ds_bpermute(a0, P[2*ks+1][0]);
            sb.u[0] = (unsigned)(hi ? f : e);
            e = __builtin_amdgcn_ds_bpermute(a0, P[2*ks][1]);
            f = __builtin_amdgcn_ds_bpermute(a0, P[2*ks+1][1]);
            sb.u[1] = (unsigned)(hi ? f : e);
            e = __builtin_amdgcn_ds_bpermute(a1, P[2*ks][0]);
            f = __builtin_amdgcn_ds_bpermute(a1, P[2*ks+1][0]);
            sb.u[2] = (unsigned)(hi ? f : e);
            e = __builtin_amdgcn_ds_bpermute(a1, P[2*ks][1]);
            f = __builtin_amdgcn_ds_bpermute(a1, P[2*ks+1][1]);
            sb.u[3] = (unsigned)(hi ? f : e);
            SB[ks] = sb.v;
        }

        // Y = kn @ S
        f32x4 Y[2] = {Z, Z};
#pragma unroll
        for (int ks = 0; ks < 4; ++ks)
#pragma unroll
        for (int mt = 0; mt < 2; ++mt)
            Y[mt] = MFMA16(cur[mt][ks], SB[ks], Y[mt]);

        // prefetch next chunk's kn (stays in flight — no barriers anywhere)
        int chn = (ch + 1 < NCH) ? ch + 1 : NCH - 1;
        loadK(chn, nxt);

        // S-update A-frags: kn^T from knR
        LGKM_WAIT();
        bf16x8 knA[8];
#pragma unroll
        for (int t = 0; t < 8; ++t){
            unsigned short rj[8];
#pragma unroll
            for (int j = 0; j < 8; ++j)
                rj[j] = knR[(q8 + j) * 136 + ((q8 + j) >> 3) * 16 + 16*t + ln15];
            U8 kk;
            kk.u[0] = (unsigned)rj[0] | ((unsigned)rj[1] << 16);
            kk.u[1] = (unsigned)rj[2] | ((unsigned)rj[3] << 16);
            kk.u[2] = (unsigned)rj[4] | ((unsigned)rj[5] << 16);
            kk.u[3] = (unsigned)rj[6] | ((unsigned)rj[7] << 16);
            knA[t] = kk.v;
        }

        // O partial = qn @ S   (independent of X/U — overlaps LDS latency)
        f32x4 O[2] = {Z, Z};
#pragma unroll
        for (int ks = 0; ks < 4; ++ks)
#pragma unroll
        for (int mt = 0; mt < 2; ++mt)
            O[mt] = MFMA16(qA[mt][ks], SB[ks], O[mt]);

        // X = beta*(v - Y)  -> Xt (c x i)
#pragma unroll
        for (int mt = 0; mt < 2; ++mt){
            unsigned int w0 = pk2(bt[4*mt+0] * (vv[4*mt+0] - Y[mt][0]),
                                  bt[4*mt+1] * (vv[4*mt+1] - Y[mt][1]));
            unsigned int w1 = pk2(bt[4*mt+2] * (vv[4*mt+2] - Y[mt][2]),
                                  bt[4*mt+3] * (vv[4*mt+3] - Y[mt][3]));
            *(unsigned int*)&Xt[ln15][16*mt + 4*quad]     = w0;
            *(unsigned int*)&Xt[ln15][16*mt + 4*quad + 2] = w1;
        }
        LGKM_WAIT();
        bf16x8 Xb = *(const bf16x8*)&Xt[ln15][q8];

        // U = T @ X
        f32x4 U[2];
#pragma unroll
        for (int mt = 0; mt < 2; ++mt) U[mt] = MFMA16(tA[mt], Xb, Z);
#pragma unroll
        for (int mt = 0; mt < 2; ++mt){
            unsigned int w0 = pk2(U[mt][0], U[mt][1]);
            unsigned int w1 = pk2(U[mt][2], U[mt][3]);
            *(unsigned int*)&ut[ln15][16*mt + 4*quad]     = w0;
            *(unsigned int*)&ut[ln15][16*mt + 4*quad + 2] = w1;
        }
        LGKM_WAIT();
        bf16x8 uB = *(const bf16x8*)&ut[ln15][q8];

        // O += attn @ U ; store
#pragma unroll
        for (int mt = 0; mt < 2; ++mt) O[mt] = MFMA16(aA[mt], uB, O[mt]);
#pragma unroll
        for (int mt = 0; mt < 2; ++mt)
#pragma unroll
        for (int rg = 0; rg < 4; ++rg)
            out[(row0 + 16*mt + 4*quad + rg) * DV + c0 + ln15] = O[mt][rg];

        // S += kn^T @ U
#pragma unroll
        for (int t = 0; t < 8; ++t)
            Sacc[t] = MFMA16(knA[t], uB, Sacc[t]);
    };

    for (int ch = 0; ch < NCH; ch += 2){
        body(ch,     kAa, kAb);
        body(ch + 1, kAb, kAa);
    }
}

// ---------------- Fallback (round-1 fused kernel) if ws too small ----------

__global__ __launch_bounds__(512, 1)
void deltanet_fused(const float* __restrict__ q, const float* __restrict__ k,
                    const float* __restrict__ v, const float* __restrict__ beta,
                    float* __restrict__ out)
{
    const int bh = blockIdx.x;
    const int tid = threadIdx.x;
    const int n = L_SEQ / CHUNK;

    __shared__ float S[DK][DV + 1];
    __shared__ float qs[CHUNK][DK + 1];
    __shared__ float ks[CHUNK][DK + 1];
    __shared__ float vs[CHUNK][DV + 1];
    __shared__ float kbs[CHUNK][DK + 1];
    __shared__ float T[CHUNK][CHUNK + 1];
    __shared__ float at[CHUNK][CHUNK + 1];
    __shared__ float bet[CHUNK];

    for (int idx = tid; idx < DK * DV; idx += 512)
        S[idx / DV][idx % DV] = 0.f;
    __syncthreads();

    const size_t base_bh = (size_t)bh * L_SEQ;

    for (int ch = 0; ch < n; ++ch){
        const size_t row0 = base_bh + (size_t)ch * CHUNK;
        for (int idx = tid; idx < CHUNK * DK; idx += 512){
            int r = idx >> 7, c = idx & 127;
            size_t g = (row0 + (size_t)r) * DK + c;
            qs[r][c] = q[g]; ks[r][c] = k[g]; vs[r][c] = v[g];
        }
        if (tid < CHUNK) bet[tid] = beta[row0 + tid];
        __syncthreads();
        if (tid < 64){
            int r = tid & 31;
            const float* src = (tid < 32) ? &qs[r][0] : &ks[r][0];
            float s = 0.f;
            for (int d = 0; d < DK; ++d){ float x = src[d]; s += x * x; }
            at[(tid < 32) ? 0 : 1][r] = 1.0f / sqrtf(s + 1e-6f);
        }
        __syncthreads();
        for (int idx = tid; idx < CHUNK * DK; idx += 512){
            int r = idx >> 7, c = idx & 127;
            float qq = qs[r][c] * at[0][r];
            float kk = ks[r][c] * at[1][r];
            float b = bet[r];
            qs[r][c] = qq; ks[r][c] = kk; kbs[r][c] = kk * b; vs[r][c] *= b;
        }
        __syncthreads();
        for (int idx = tid; idx < CHUNK * CHUNK; idx += 512){
            int i = idx >> 5, j = idx & 31;
            float s = 0.f;
            if (j < i){
                for (int d = 0; d < DK; ++d) s += kbs[i][d] * ks[j][d];
                s = -s;
            }
            T[i][j] = s;
        }
        __syncthreads();
        for (int i = 1; i < CHUNK; ++i){
            float upd = 0.f;
            if (tid < i){
                int j = tid;
                for (int kk = j + 1; kk < i; ++kk) upd += T[i][kk] * T[kk][j];
            }
            __syncthreads();
            if (tid < i) T[i][tid] += upd;
            __syncthreads();
        }
        if (tid < CHUNK) T[tid][tid] = 1.0f;
        __syncthreads();
        {
            int c = tid & 127;
            int i0 = (tid >> 7) * 8;
            float uacc[8], wacc[8];
#pragma unroll
            for (int r = 0; r < 8; ++r){ uacc[r] = 0.f; wacc[r] = 0.f; }
            for (int j = 0; j < CHUNK; ++j){
                float vvv = vs[j][c], kb = kbs[j][c];
#pragma unroll
                for (int r = 0; r < 8; ++r){
                    float tt = T[i0 + r][j];
                    uacc[r] += tt * vvv; wacc[r] += tt * kb;
                }
            }
            __syncthreads();
#pragma unroll
            for (int r = 0; r < 8; ++r){ vs[i0 + r][c] = uacc[r]; kbs[i0 + r][c] = wacc[r]; }
        }
        __syncthreads();
        for (int idx = tid; idx < CHUNK * CHUNK; idx += 512){
            int i = idx >> 5, j = idx & 31;
            float s = 0.f;
            if (j <= i) for (int d = 0; d < DK; ++d) s += qs[i][d] * ks[j][d];
            at[i][j] = s;
        }
        __syncthreads();
        {
            int c = tid & 127;
            int i0 = (tid >> 7) * 8;
            float acc[8];
#pragma unroll
            for (int r = 0; r < 8; ++r) acc[r] = 0.f;
            for (int d = 0; d < DK; ++d){
                float sv = S[d][c];
#pragma unroll
                for (int r = 0; r < 8; ++r) acc[r] += kbs[i0 + r][d] * sv;
            }
#pragma unroll
            for (int r = 0; r < 8; ++r) vs[i0 + r][c] -= acc[r];
        }
        __syncthreads();
        {
            int c = tid & 127;
            int i0 = (tid >> 7) * 8;
            float acc[8];
#pragma unroll
            for (int r = 0; r < 8; ++r) acc[r] = 0.f;
            for (int d = 0; d < DK; ++d){
                float sv = S[d][c];
#pragma unroll
                for (int r = 0; r < 8; ++r) acc[r] += qs[i0 + r][d] * sv;
            }
            for (int j = 0; j < CHUNK; ++j){
                float uv = vs[j][c];
#pragma unroll
                for (int r = 0; r < 8; ++r) acc[r] += at[i0 + r][j] * uv;
            }
#pragma unroll
            for (int r = 0; r < 8; ++r)
                out[(row0 + (size_t)(i0 + r)) * DV + c] = acc[r];
        }
        __syncthreads();
        {
            int c = tid & 127;
            int d0 = (tid >> 7) * 32;
            float acc[32];
#pragma unroll
            for (int r = 0; r < 32; ++r) acc[r] = 0.f;
            for (int i = 0; i < CHUNK; ++i){
                float uv = vs[i][c];
#pragma unroll
                for (int r = 0; r < 32; ++r) acc[r] += ks[i][d0 + r] * uv;
            }
#pragma unroll
            for (int r = 0; r < 32; ++r) S[d0 + r][c] += acc[r];
        }
        __syncthreads();
    }
}

extern "C" void kernel_launch(void* const* d_in, const int* in_sizes, int n_in,
                              void* d_out, int out_size, void* d_ws, size_t ws_size,
                              hipStream_t stream) {
    const float* q = (const float*)d_in[0];
    const float* k = (const float*)d_in[1];
    const float* v = (const float*)d_in[2];
    const float* beta = (const float*)d_in[3];
    float* out = (float*)d_out;

    const size_t QK = (size_t)BH * L_SEQ * DK;       // 16,777,216
    const size_t TA = (size_t)BH * NCH * 1024;       //  4,194,304
    const size_t need = (2 * QK + 2 * TA) * sizeof(unsigned short); // ~84 MB

    if (ws_size >= need){
        unsigned short* qwp = (unsigned short*)d_ws;
        unsigned short* kwp = qwp + QK;
        unsigned short* Twp = kwp + QK;
        unsigned short* Awp = Twp + TA;
        prep_kernel<<<BH * NCH, 64, 0, stream>>>(q, k, beta, qwp, kwp, Twp, Awp);
        scan_kernel<<<BH * 8, 64, 0, stream>>>(v, beta, qwp, kwp, Twp, Awp, out);
    } else {
        deltanet_fused<<<BH, 512, 0, stream>>>(q, k, v, beta, out);
    }
}